// Round 10
// baseline (381.085 us; speedup 1.0000x reference)
//
#include <hip/hip_runtime.h>

#define VOC 49408
#define TD 512
#define DM 768
#define NCOLG2 193   // VOC / 256  (k_cos col-groups)
#define PV_S 32

typedef __attribute__((ext_vector_type(8))) short bf16x8;
typedef __attribute__((ext_vector_type(4))) short bf16x4;
typedef __attribute__((ext_vector_type(4))) float f32x4;

__device__ __forceinline__ unsigned short f2bf(float f) {
  unsigned int u = __float_as_uint(f);
  u += 0x7fffu + ((u >> 16) & 1u);   // RNE
  return (unsigned short)(u >> 16);
}

__device__ __forceinline__ float bf2f(unsigned short h) {
  return __uint_as_float(((unsigned int)h) << 16);
}

__device__ __forceinline__ void gload16(const void* g, const void* l) {
  __builtin_amdgcn_global_load_lds(
      (const __attribute__((address_space(1))) void*)g,
      (__attribute__((address_space(3))) void*)l, 16, 0, 0);
}

// ---------------------------------------------------------------- K1: proj + normalize
__global__ __launch_bounds__(256) void k_proj(const float* __restrict__ kw,
                                              const float* __restrict__ Wp,
                                              const float* __restrict__ bp,
                                              unsigned short* __restrict__ kwn) {
  __shared__ float row_lds[4 * DM];
  __shared__ float rsum[4][4];
  __shared__ float rinv_s[4];
  const int t = threadIdx.x;
  const int rb = blockIdx.x * 4;
  for (int i = 0; i < 12; ++i) {
    int idx = i * 256 + t;
    row_lds[idx] = kw[(size_t)rb * DM + idx];
  }
  __syncthreads();
  float acc[4][2] = {};
  for (int m = 0; m < DM; ++m) {
    float w0 = Wp[m * TD + t];
    float w1 = Wp[m * TD + t + 256];
#pragma unroll
    for (int r = 0; r < 4; ++r) {
      float kv = row_lds[r * DM + m];
      acc[r][0] = fmaf(kv, w0, acc[r][0]);
      acc[r][1] = fmaf(kv, w1, acc[r][1]);
    }
  }
  const float b0 = bp[t], b1 = bp[t + 256];
  float p[4];
#pragma unroll
  for (int r = 0; r < 4; ++r) {
    acc[r][0] += b0;
    acc[r][1] += b1;
    p[r] = acc[r][0] * acc[r][0] + acc[r][1] * acc[r][1];
  }
#pragma unroll
  for (int off = 32; off; off >>= 1) {
#pragma unroll
    for (int r = 0; r < 4; ++r) p[r] += __shfl_down(p[r], off);
  }
  const int lane = t & 63, wv = t >> 6;
  if (lane == 0) {
#pragma unroll
    for (int r = 0; r < 4; ++r) rsum[r][wv] = p[r];
  }
  __syncthreads();
  if (t < 4) {
    float s = rsum[t][0] + rsum[t][1] + rsum[t][2] + rsum[t][3];
    rinv_s[t] = 1.0f / fmaxf(sqrtf(s), 1e-8f);
  }
  __syncthreads();
#pragma unroll
  for (int r = 0; r < 4; ++r) {
    float ri = rinv_s[r];
    kwn[(size_t)(rb + r) * TD + t] = f2bf(acc[r][0] * ri);
    kwn[(size_t)(rb + r) * TD + t + 256] = f2bf(acc[r][1] * ri);
  }
}

// ---------------------------------------------------------------- K2: one We pass -> embB (raw bf16) + rnormv
__global__ __launch_bounds__(256) void k_norms(const float* __restrict__ We,
                                               unsigned short* __restrict__ embB,
                                               float* __restrict__ rnormv) {
  const int t = threadIdx.x;
  const int lane = t & 63, w = t >> 6;
  const int v = blockIdx.x * 4 + w;
  const float* rowp = We + (size_t)v * TD;
  float4 a = *(const float4*)(rowp + lane * 8);
  float4 b = *(const float4*)(rowp + lane * 8 + 4);
  bf16x8 o;
  o[0] = (short)f2bf(a.x); o[1] = (short)f2bf(a.y);
  o[2] = (short)f2bf(a.z); o[3] = (short)f2bf(a.w);
  o[4] = (short)f2bf(b.x); o[5] = (short)f2bf(b.y);
  o[6] = (short)f2bf(b.z); o[7] = (short)f2bf(b.w);
  *(bf16x8*)(embB + (size_t)v * TD + lane * 8) = o;
  float ss = a.x * a.x + a.y * a.y + a.z * a.z + a.w * a.w +
             b.x * b.x + b.y * b.y + b.z * b.z + b.w * b.w;
#pragma unroll
  for (int off = 1; off < 64; off <<= 1) ss += __shfl_xor(ss, off);
  if (lane == 0) rnormv[v] = 1.0f / fmaxf(sqrtf(ss), 1e-8f);
}

// ---------------------------------------------------------------- K2b: transpose embB -> embT [d][v]
__global__ __launch_bounds__(256) void k_transpose(const unsigned short* __restrict__ embB,
                                                   unsigned short* __restrict__ embT) {
  __shared__ unsigned short tile[64 * 72];
  const int t = threadIdx.x;
  const int d0 = blockIdx.x * 64, v0 = blockIdx.y * 64;
#pragma unroll
  for (int p = 0; p < 2; ++p) {
    int vl = p * 32 + (t >> 3), ch = t & 7;
    *(bf16x8*)&tile[vl * 72 + ch * 8] =
        *(const bf16x8*)(embB + (size_t)(v0 + vl) * TD + d0 + ch * 8);
  }
  __syncthreads();
#pragma unroll
  for (int p = 0; p < 2; ++p) {
    int dl = p * 32 + (t >> 3), vch = t & 7;
    bf16x8 o;
#pragma unroll
    for (int i = 0; i < 8; ++i) o[i] = (short)tile[(vch * 8 + i) * 72 + dl];
    *(bf16x8*)(embT + (size_t)(d0 + dl) * VOC + v0 + vch * 8) = o;
  }
}

// ---------------------------------------------------------------- K3: cos GEMM (256x256, dbuf) + sumexp + eb=bf16(exp)
// BM=256, BN=256, BK=64. grid (4 rowg, 193 colg), 512 thr = 8 waves (64r x 128c each).
// Epilogue: cos (f32), eb = bf16(exp(cos)) via els (aliases dead dbuf smem), partials.
__global__ __launch_bounds__(512, 2) void k_cos(const unsigned short* __restrict__ kwn,
                                                const unsigned short* __restrict__ embB,
                                                const float* __restrict__ rnormv,
                                                float* __restrict__ cosd,
                                                unsigned short* __restrict__ eb,
                                                float* __restrict__ partial) {
  __shared__ unsigned short smem[2][2][256 * 64];   // [buf][op A/B] 128 KiB
  __shared__ float rs[2][256];
  const int t = threadIdx.x;
  const int lane = t & 63, w = t >> 6;       // 8 waves
  const int wr = w & 3, wc = w >> 2;         // rows wr*64.., cols wc*128..
  const int g = lane >> 4, l15 = lane & 15;
  const int rowg = blockIdx.x;               // 0..3
  const int colg = blockIdx.y;               // 0..192

  const int rl = lane >> 3;
  const int bsl = (lane & 7) ^ rl;           // pre-swizzled source chunk

  f32x4 acc[4][8];
#pragma unroll
  for (int mi = 0; mi < 4; ++mi)
#pragma unroll
    for (int ni = 0; ni < 8; ++ni)
#pragma unroll
      for (int j = 0; j < 4; ++j) acc[mi][ni][j] = 0.0f;

  const unsigned short* Ag = kwn + (size_t)(rowg * 256 + w * 8 + rl) * TD + bsl * 8;
  const unsigned short* Bg = embB + (size_t)(colg * 256 + w * 8 + rl) * TD + bsl * 8;

  // prologue: stage tile 0 into buf 0
#pragma unroll
  for (int i = 0; i < 4; ++i) {
    gload16(Ag + (size_t)(i * 64) * TD, (const void*)(&smem[0][0][(i * 64 + w * 8) * 64]));
    gload16(Bg + (size_t)(i * 64) * TD, (const void*)(&smem[0][1][(i * 64 + w * 8) * 64]));
  }
  __syncthreads();

  for (int kt = 0; kt < 8; ++kt) {
    const int buf = kt & 1;
    if (kt < 7) {
#pragma unroll
      for (int i = 0; i < 4; ++i) {
        gload16(Ag + (size_t)(i * 64) * TD + (kt + 1) * 64,
                (const void*)(&smem[buf ^ 1][0][(i * 64 + w * 8) * 64]));
        gload16(Bg + (size_t)(i * 64) * TD + (kt + 1) * 64,
                (const void*)(&smem[buf ^ 1][1][(i * 64 + w * 8) * 64]));
      }
    }
#pragma unroll
    for (int ks = 0; ks < 2; ++ks) {
      const int ch = (((ks * 4 + g) ^ (l15 & 7)) << 3);
      bf16x8 a[4];
#pragma unroll
      for (int mi = 0; mi < 4; ++mi)
        a[mi] = *(const bf16x8*)&smem[buf][0][(wr * 64 + mi * 16 + l15) * 64 + ch];
#pragma unroll
      for (int ni = 0; ni < 8; ++ni) {
        bf16x8 b = *(const bf16x8*)&smem[buf][1][(wc * 128 + ni * 16 + l15) * 64 + ch];
#pragma unroll
        for (int mi = 0; mi < 4; ++mi)
          acc[mi][ni] = __builtin_amdgcn_mfma_f32_16x16x32_bf16(a[mi], b, acc[mi][ni], 0, 0, 0);
      }
    }
    __syncthreads();   // drains next-tile gloads + syncs buffer swap
  }

  // epilogue: c = acc*rnormv[col] -> cos (f32 global), e = exp(c) -> els (LDS, 128 KiB
  // alias over the dead dbuf), per-row sumexp -> rs.
  unsigned short* els = &smem[0][0][0];   // [256 rows][256 cols] bf16, exactly 128 KiB
  const size_t rowbase = (size_t)rowg * 256 + wr * 64;
  const int colbase = colg * 256 + wc * 128;
  float rnv[8];
#pragma unroll
  for (int ni = 0; ni < 8; ++ni) rnv[ni] = rnormv[colbase + ni * 16 + l15];
#pragma unroll
  for (int mi = 0; mi < 4; ++mi) {
    float es[4] = {0.f, 0.f, 0.f, 0.f};
#pragma unroll
    for (int ni = 0; ni < 8; ++ni) {
#pragma unroll
      for (int j = 0; j < 4; ++j) {
        float c = acc[mi][ni][j] * rnv[ni];
        cosd[(rowbase + mi * 16 + g * 4 + j) * VOC + colbase + ni * 16 + l15] = c;
        float ev = __expf(c);
        es[j] += ev;
        els[(wr * 64 + mi * 16 + g * 4 + j) * 256 + wc * 128 + ni * 16 + l15] = f2bf(ev);
      }
    }
#pragma unroll
    for (int j = 0; j < 4; ++j) {
      float e = es[j];
      e += __shfl_xor(e, 1);
      e += __shfl_xor(e, 2);
      e += __shfl_xor(e, 4);
      e += __shfl_xor(e, 8);
      if (l15 == 0) rs[wc][wr * 64 + mi * 16 + g * 4 + j] = e;
    }
  }
  __syncthreads();
  // cooperative coalesced eb store: 256 rows x 32 chunks of 8 bf16
#pragma unroll
  for (int k = 0; k < 16; ++k) {
    int id = k * 512 + t;
    int r = id >> 5, c8 = id & 31;
    *(bf16x8*)(eb + (size_t)(rowg * 256 + r) * VOC + colg * 256 + c8 * 8) =
        *(const bf16x8*)&els[r * 256 + c8 * 8];
  }
  if (t < 256) {
    float srow = rs[0][t] + rs[1][t];
    partial[(size_t)colg * 1024 + rowg * 256 + t] = srow;
  }
}

// ---------------------------------------------------------------- K3b: denom reduce (1 wave per row)
__global__ __launch_bounds__(256) void k_denom(const float* __restrict__ partial,
                                               float* __restrict__ rdenom) {
  const int t = threadIdx.x;
  const int lane = t & 63, w = t >> 6;
  const int row = blockIdx.x * 4 + w;
  float s = 0.f;
  for (int c = lane; c < NCOLG2; c += 64) s += partial[(size_t)c * 1024 + row];
#pragma unroll
  for (int off = 1; off < 64; off <<= 1) s += __shfl_xor(s, off);
  if (lane == 0) rdenom[row] = 1.0f / s;
}

// ---------------------------------------------------------------- K4: PV GEMM on eb (pure 2-gload dbuf) + prob
// BM=256, BN=256, BK=64. grid (4 rowg, 2 colg, 32 s) = 256 blocks, 512 thr/8 waves.
// A = eb gload16, B = embT gload16 (both linear dest + pre-swizzled src, dbuf).
// prob tile kt = f32(A-LDS)*rdv, written by the colg==(kt&1) block. kpart unnormalized.
__global__ __launch_bounds__(512, 2) void k_pv(const unsigned short* __restrict__ eb,
                                               const unsigned short* __restrict__ embT,
                                               const float* __restrict__ rdenom,
                                               float* __restrict__ prob,
                                               float* __restrict__ kpart) {
  __shared__ unsigned short smem[2][2][256 * 64];   // [buf][A/B] 128 KiB
  const int t = threadIdx.x;
  const int lane = t & 63, w = t >> 6;        // 8 waves
  const int wr = w & 3, wc = w >> 2;          // per-wave 64 rows x 128 d
  const int g = lane >> 4, l15 = lane & 15;
  const int rowg = blockIdx.x;                // 0..3
  const int colg = blockIdx.y;                // 0..1
  const int s = blockIdx.z;                   // 0..31
  const int t0 = s * 24 + (s < 4 ? s : 4);
  const int t1 = t0 + 24 + (s < 4 ? 1 : 0);

  const int rl = lane >> 3;
  const int bsl = (lane & 7) ^ rl;            // pre-swizzled source chunk

  // prob path: thread owns row ar (0..255), half ah (4 of 8 chunks)
  const int ar = t >> 1, ah = t & 1;
  const int grow = rowg * 256 + ar;
  const float rdv = rdenom[grow];
  float* pbase = prob + (size_t)grow * VOC;

  f32x4 acc[4][8];
#pragma unroll
  for (int mi = 0; mi < 4; ++mi)
#pragma unroll
    for (int ni = 0; ni < 8; ++ni)
#pragma unroll
      for (int j = 0; j < 4; ++j) acc[mi][ni][j] = 0.0f;

  const unsigned short* Ag = eb + (size_t)(rowg * 256 + w * 8 + rl) * VOC + bsl * 8;
  const unsigned short* Bg = embT + (size_t)(colg * 256 + w * 8 + rl) * VOC + bsl * 8;

  // prologue: stage tile t0 into buf 0
#pragma unroll
  for (int i = 0; i < 4; ++i) {
    gload16(Ag + (size_t)(i * 64) * VOC + t0 * 64, (const void*)(&smem[0][0][(i * 64 + w * 8) * 64]));
    gload16(Bg + (size_t)(i * 64) * VOC + t0 * 64, (const void*)(&smem[0][1][(i * 64 + w * 8) * 64]));
  }
  __syncthreads();

  for (int kt = t0; kt < t1; ++kt) {
    const int buf = (kt - t0) & 1;
    if (kt + 1 < t1) {
#pragma unroll
      for (int i = 0; i < 4; ++i) {
        gload16(Ag + (size_t)(i * 64) * VOC + (kt + 1) * 64,
                (const void*)(&smem[buf ^ 1][0][(i * 64 + w * 8) * 64]));
        gload16(Bg + (size_t)(i * 64) * VOC + (kt + 1) * 64,
                (const void*)(&smem[buf ^ 1][1][(i * 64 + w * 8) * 64]));
      }
    }
    // MFMA(kt) from buf
#pragma unroll
    for (int ks = 0; ks < 2; ++ks) {
      const int ch = (((ks * 4 + g) ^ (l15 & 7)) << 3);
      bf16x8 a[4];
#pragma unroll
      for (int mi = 0; mi < 4; ++mi)
        a[mi] = *(const bf16x8*)&smem[buf][0][(wr * 64 + mi * 16 + l15) * 64 + ch];
#pragma unroll
      for (int ni = 0; ni < 8; ++ni) {
        bf16x8 b = *(const bf16x8*)&smem[buf][1][(wc * 128 + ni * 16 + l15) * 64 + ch];
#pragma unroll
        for (int mi = 0; mi < 4; ++mi)
          acc[mi][ni] = __builtin_amdgcn_mfma_f32_16x16x32_bf16(a[mi], b, acc[mi][ni], 0, 0, 0);
      }
    }
    // prob(kt) from the resident A tile (balanced across colg)
    if (colg == (kt & 1)) {
#pragma unroll
      for (int i = 0; i < 4; ++i) {
        const int c8 = 2 * i + ah;
        bf16x8 ev = *(const bf16x8*)&smem[buf][0][ar * 64 + ((c8 ^ (ar & 7)) << 3)];
        float4 o0, o1;
        o0.x = bf2f((unsigned short)ev[0]) * rdv;
        o0.y = bf2f((unsigned short)ev[1]) * rdv;
        o0.z = bf2f((unsigned short)ev[2]) * rdv;
        o0.w = bf2f((unsigned short)ev[3]) * rdv;
        o1.x = bf2f((unsigned short)ev[4]) * rdv;
        o1.y = bf2f((unsigned short)ev[5]) * rdv;
        o1.z = bf2f((unsigned short)ev[6]) * rdv;
        o1.w = bf2f((unsigned short)ev[7]) * rdv;
        *(float4*)(pbase + (size_t)kt * 64 + c8 * 8) = o0;
        *(float4*)(pbase + (size_t)kt * 64 + c8 * 8 + 4) = o1;
      }
    }
    __syncthreads();   // drains buf^1 gloads + swap
  }

  // epilogue: kpart[s][row][d] (unnormalized; rdv applied in k_kwout)
#pragma unroll
  for (int mi = 0; mi < 4; ++mi)
#pragma unroll
    for (int ni = 0; ni < 8; ++ni)
#pragma unroll
      for (int j = 0; j < 4; ++j)
        kpart[((size_t)s * 1024 + rowg * 256 + wr * 64 + mi * 16 + g * 4 + j) * TD +
              colg * 256 + wc * 128 + ni * 16 + l15] = acc[mi][ni][j];
}

// ---------------------------------------------------------------- K5: kw_out reduce (+rdv)
__global__ __launch_bounds__(256) void k_kwout(const float* __restrict__ kpart,
                                               const float* __restrict__ rdenom,
                                               float* __restrict__ outp) {
  const int gid = blockIdx.x * 256 + threadIdx.x;
  const int row = gid >> 7;
  float4 s = {0.f, 0.f, 0.f, 0.f};
#pragma unroll
  for (int sp = 0; sp < PV_S; ++sp) {
    float4 v = *(const float4*)(kpart + (size_t)sp * 524288 + gid * 4);
    s.x += v.x; s.y += v.y; s.z += v.z; s.w += v.w;
  }
  const float rdv = rdenom[row];
  float4 o;
  o.x = s.x * rdv; o.y = s.y * rdv; o.z = s.z * rdv; o.w = s.w * rdv;
  *(float4*)(outp + gid * 4) = o;
}

extern "C" void kernel_launch(void* const* d_in, const int* in_sizes, int n_in,
                              void* d_out, int out_size, void* d_ws, size_t ws_size,
                              hipStream_t stream) {
  const float* kw = (const float*)d_in[0];
  const float* Wp = (const float*)d_in[1];
  const float* bp = (const float*)d_in[2];
  const float* We = (const float*)d_in[3];
  float* out = (float*)d_out;
  char* ws = (char*)d_ws;

  unsigned short* embT = (unsigned short*)ws;                       // 50,593,792
  unsigned short* embB = (unsigned short*)(ws + 50593792);          // 50,593,792
  unsigned short* kwn = (unsigned short*)(ws + 101187584);          // 1,048,576
  float* rnormv = (float*)(ws + 102236160);                         // 197,632
  float* partial = (float*)(ws + 102433792);                        // 790,528
  float* rdenom = (float*)(ws + 103224320);                         // 4,096
  unsigned short* eb = (unsigned short*)(ws + 103228416);           // 101,187,584
  float* kpart = (float*)(ws + 204416000);                          // 67,108,864

  float* kwout = out;
  float* prob = out + 524288;
  float* cosd = out + 51118080;

  hipLaunchKernelGGL(k_proj, dim3(256), dim3(256), 0, stream, kw, Wp, bp, kwn);
  hipLaunchKernelGGL(k_norms, dim3(12352), dim3(256), 0, stream, We, embB, rnormv);
  hipLaunchKernelGGL(k_transpose, dim3(8, 772), dim3(256), 0, stream, embB, embT);
  hipLaunchKernelGGL(k_cos, dim3(4, NCOLG2), dim3(512), 0, stream, kwn, embB, rnormv,
                     cosd, eb, partial);
  hipLaunchKernelGGL(k_denom, dim3(256), dim3(256), 0, stream, partial, rdenom);
  hipLaunchKernelGGL(k_pv, dim3(4, 2, PV_S), dim3(512), 0, stream, eb, embT, rdenom,
                     prob, kpart);
  hipLaunchKernelGGL(k_kwout, dim3(512), dim3(256), 0, stream, kpart, rdenom, kwout);
}